// Round 1
// baseline (1748.849 us; speedup 1.0000x reference)
//
#include <hip/hip_runtime.h>
#include <math.h>

#define NN 50000
#define EE 800000
#define RR 4
#define FF 256
#define HH 128
#define OO 32
#define BB 10000
#define EPSV 1e-5f

// ---------------- CSR build ----------------

__global__ void k_count(const int* __restrict__ edges, int* __restrict__ deg) {
    int r = blockIdx.y;
    int e = blockIdx.x * blockDim.x + threadIdx.x;
    if (e < EE) {
        int dst = edges[(size_t)r * 2 * EE + EE + e];
        atomicAdd(&deg[r * NN + dst], 1);
    }
}

__global__ void k_scan(const int* __restrict__ deg, int* __restrict__ offs,
                       int* __restrict__ cursor, float* __restrict__ dinv) {
    int r = blockIdx.x;
    int t = threadIdx.x;
    const int C = (NN + 255) / 256;  // 196
    __shared__ int s[256];
    int begin = t * C;
    int end = begin + C; if (end > NN) end = NN;
    int sum = 0;
    for (int i = begin; i < end; ++i) sum += deg[r * NN + i];
    s[t] = sum;
    __syncthreads();
    for (int off = 1; off < 256; off <<= 1) {
        int u = (t >= off) ? s[t - off] : 0;
        __syncthreads();
        s[t] += u;
        __syncthreads();
    }
    int run = s[t] - sum;  // exclusive prefix
    for (int i = begin; i < end; ++i) {
        int d = deg[r * NN + i];
        offs[r * (NN + 1) + i] = run;
        cursor[r * NN + i] = run;
        dinv[r * NN + i] = rsqrtf((float)(d + 1));  // +1 self loop
        run += d;
    }
    if (t == 255) offs[r * (NN + 1) + NN] = EE;
}

__global__ void k_fill(const int* __restrict__ edges, int* __restrict__ cursor,
                       int* __restrict__ csr) {
    int r = blockIdx.y;
    int e = blockIdx.x * blockDim.x + threadIdx.x;
    if (e < EE) {
        int src = edges[(size_t)r * 2 * EE + e];
        int dst = edges[(size_t)r * 2 * EE + EE + e];
        int pos = atomicAdd(&cursor[r * NN + dst], 1);
        csr[(size_t)r * EE + pos] = src;
    }
}

// ---------------- dense GEMM  C[N][BN] = A[N][K1] * W[K1][BN] ----------------

template <int K1, int BN>
__global__ void k_gemm(const float* __restrict__ A, const float* __restrict__ W,
                       float* __restrict__ C) {
    constexpr int BM = 64, BK = 32;
    constexpr int TN = 4;
    constexpr int TNG = BN / TN;                 // 32 or 8
    constexpr int TM = (BM * BN) / (256 * TN);   // 8 or 2
    __shared__ float As[BK][BM + 1];
    __shared__ float Ws[BK][BN];
    int t = threadIdx.x;
    int row0 = blockIdx.x * BM;
    int cg = t % TNG, rg = t / TNG;
    float acc[TM][TN];
#pragma unroll
    for (int i = 0; i < TM; ++i)
#pragma unroll
        for (int j = 0; j < TN; ++j) acc[i][j] = 0.f;

    for (int k0 = 0; k0 < K1; k0 += BK) {
        // A tile: BM rows x BK k  (8 consecutive floats per thread)
        {
            int rr = t / 4, kq = t % 4;
            int grow = row0 + rr;
            if (grow < NN) {
                const float* ap = A + (size_t)grow * K1 + k0 + kq * 8;
#pragma unroll
                for (int j = 0; j < 8; ++j) As[kq * 8 + j][rr] = ap[j];
            } else {
#pragma unroll
                for (int j = 0; j < 8; ++j) As[kq * 8 + j][rr] = 0.f;
            }
        }
        // W tile: rows k0..k0+BK-1, all BN cols — contiguous in row-major W
        {
            constexpr int PT = (BK * BN / 4) / 256;  // float4 per thread: 4 or 1
            const float4* W4 = (const float4*)(W + (size_t)k0 * BN);
            float4* Ws4 = (float4*)&Ws[0][0];
#pragma unroll
            for (int i = 0; i < PT; ++i) {
                int f = t + i * 256;
                Ws4[f] = W4[f];
            }
        }
        __syncthreads();
#pragma unroll
        for (int k = 0; k < BK; ++k) {
            float a[TM], w[TN];
#pragma unroll
            for (int i = 0; i < TM; ++i) a[i] = As[k][rg * TM + i];
            float4 wv = *(const float4*)&Ws[k][cg * TN];
            w[0] = wv.x; w[1] = wv.y; w[2] = wv.z; w[3] = wv.w;
#pragma unroll
            for (int i = 0; i < TM; ++i)
#pragma unroll
                for (int j = 0; j < TN; ++j) acc[i][j] += a[i] * w[j];
        }
        __syncthreads();
    }
#pragma unroll
    for (int i = 0; i < TM; ++i) {
        int grow = row0 + rg * TM + i;
        if (grow < NN) {
            float4 v = make_float4(acc[i][0], acc[i][1], acc[i][2], acc[i][3]);
            *(float4*)(C + (size_t)grow * BN + cg * TN) = v;
        }
    }
}

// ---------------- aggregation:  Y[n] = dinv[n] * (sum_e dinv[s] X[s] + dinv[n] X[n]) --------

template <int D>
__global__ void k_agg(const float* __restrict__ X, float* __restrict__ Y,
                      const int* __restrict__ offs, const int* __restrict__ csr,
                      const float* __restrict__ dinv) {
    int tid = threadIdx.x;
    if constexpr (D == 128) {
        int wid = tid >> 6, lane = tid & 63;
        int n = blockIdx.x * 4 + wid;
        if (n >= NN) return;
        int c = lane * 2;
        float ax = 0.f, ay = 0.f;
        int s0 = offs[n], s1 = offs[n + 1];
        for (int e = s0; e < s1; ++e) {
            int s = csr[e];
            float w = dinv[s];
            float2 v = *(const float2*)(X + (size_t)s * D + c);
            ax += w * v.x; ay += w * v.y;
        }
        float dn = dinv[n];
        float2 v = *(const float2*)(X + (size_t)n * D + c);
        ax += dn * v.x; ay += dn * v.y;
        float2 o; o.x = ax * dn; o.y = ay * dn;
        *(float2*)(Y + (size_t)n * D + c) = o;
    } else {
        int wid = tid >> 6, lane = tid & 63;
        int sub = lane >> 5, col = lane & 31;
        int n = blockIdx.x * 8 + wid * 2 + sub;
        if (n >= NN) return;
        float acc = 0.f;
        int s0 = offs[n], s1 = offs[n + 1];
        for (int e = s0; e < s1; ++e) {
            int s = csr[e];
            acc += dinv[s] * X[(size_t)s * D + col];
        }
        float dn = dinv[n];
        acc += dn * X[(size_t)n * D + col];
        Y[(size_t)n * D + col] = acc * dn;
    }
}

// ---------------- batchnorm ----------------

template <int D>
__global__ void k_stats(const float* __restrict__ X, float* __restrict__ partial) {
    constexpr int BY = 256 / D;
    int c = threadIdx.x;
    int ty = threadIdx.y;
    float s = 0.f, ss = 0.f;
    for (int row = blockIdx.x * BY + ty; row < NN; row += gridDim.x * BY) {
        float v = X[(size_t)row * D + c];
        s += v; ss += v * v;
    }
    __shared__ float ls[BY][D];
    __shared__ float lss[BY][D];
    ls[ty][c] = s; lss[ty][c] = ss;
    __syncthreads();
    if (ty == 0) {
#pragma unroll
        for (int y = 1; y < BY; ++y) { s += ls[y][c]; ss += lss[y][c]; }
        partial[blockIdx.x * 2 * D + c] = s;
        partial[blockIdx.x * 2 * D + D + c] = ss;
    }
}

template <int D>
__global__ void k_finalize(const float* __restrict__ partial, const float* __restrict__ g,
                           const float* __restrict__ be, float* __restrict__ ab) {
    int c = threadIdx.x;
    float s = 0.f, ss = 0.f;
    for (int i = 0; i < 256; ++i) {
        s += partial[i * 2 * D + c];
        ss += partial[i * 2 * D + D + c];
    }
    float mean = s / (float)NN;
    float var = ss / (float)NN - mean * mean;
    float rstd = rsqrtf(var + EPSV);
    float a = g[c] * rstd;
    ab[c] = a;
    ab[D + c] = be[c] - mean * a;
}

template <int D>
__global__ void k_apply(float* __restrict__ X, const float* __restrict__ ab) {
    constexpr int TOT4 = NN * D / 4;
    int idx = blockIdx.x * blockDim.x + threadIdx.x;
    if (idx >= TOT4) return;
    int c4 = idx % (D / 4);
    float4 x = ((const float4*)X)[idx];
    float4 a = ((const float4*)ab)[c4];
    float4 b = ((const float4*)ab)[D / 4 + c4];
    float4 y;
    y.x = fmaxf(a.x * x.x + b.x, 0.f);
    y.y = fmaxf(a.y * x.y + b.y, 0.f);
    y.z = fmaxf(a.z * x.z + b.z, 0.f);
    y.w = fmaxf(a.w * x.w + b.w, 0.f);
    ((float4*)X)[idx] = y;
}

// ---------------- gather + log_softmax ----------------

__global__ void k_lsm(const float* __restrict__ X, const int* __restrict__ batch,
                      float* __restrict__ out, int r) {
    int tx = threadIdx.x;  // 32 = OO
    int b = blockIdx.x * blockDim.y + threadIdx.y;
    if (b >= BB) return;
    int node = batch[b];
    float v = X[(size_t)node * OO + tx];
    float m = v;
#pragma unroll
    for (int off = 16; off; off >>= 1) m = fmaxf(m, __shfl_xor(m, off, 32));
    float e = expf(v - m);
    float sum = e;
#pragma unroll
    for (int off = 16; off; off >>= 1) sum += __shfl_xor(sum, off, 32);
    out[(size_t)b * (RR * OO) + r * OO + tx] = v - m - logf(sum);
}

// ---------------- host ----------------

extern "C" void kernel_launch(void* const* d_in, const int* in_sizes, int n_in,
                              void* d_out, int out_size, void* d_ws, size_t ws_size,
                              hipStream_t stream) {
    const float* features = (const float*)d_in[0];
    const int* edges = (const int*)d_in[1];
    const int* batch = (const int*)d_in[2];
    const float* W1 = (const float*)d_in[3];
    const float* g1 = (const float*)d_in[5];
    const float* be1 = (const float*)d_in[6];
    const float* W2 = (const float*)d_in[7];
    const float* g2 = (const float*)d_in[9];
    const float* be2 = (const float*)d_in[10];
    float* out = (float*)d_out;

    char* p = (char*)d_ws;
    auto carve = [&](size_t bytes) {
        void* q = (void*)p;
        p += (bytes + 255) & ~(size_t)255;
        return q;
    };
    int* deg = (int*)carve((size_t)RR * NN * 4);
    float* dinv = (float*)carve((size_t)RR * NN * 4);
    int* offs = (int*)carve((size_t)RR * (NN + 1) * 4);
    int* cursor = (int*)carve((size_t)RR * NN * 4);
    int* csr = (int*)carve((size_t)RR * EE * 4);
    float* bufA = (float*)carve((size_t)NN * HH * 4);
    float* bufB = (float*)carve((size_t)NN * HH * 4);
    float* bufC = (float*)carve((size_t)NN * OO * 4);
    float* bufD = (float*)carve((size_t)NN * OO * 4);
    float* partial = (float*)carve((size_t)256 * 2 * HH * 4);
    float* ab = (float*)carve((size_t)2 * HH * 4);

    hipMemsetAsync(deg, 0, (size_t)RR * NN * 4, stream);
    k_count<<<dim3((EE + 255) / 256, RR), 256, 0, stream>>>(edges, deg);
    k_scan<<<RR, 256, 0, stream>>>(deg, offs, cursor, dinv);
    k_fill<<<dim3((EE + 255) / 256, RR), 256, 0, stream>>>(edges, cursor, csr);

    for (int r = 0; r < RR; ++r) {
        const int* offs_r = offs + r * (NN + 1);
        const int* csr_r = csr + (size_t)r * EE;
        const float* dinv_r = dinv + (size_t)r * NN;

        k_gemm<FF, HH><<<(NN + 63) / 64, 256, 0, stream>>>(features, W1 + (size_t)r * FF * HH, bufA);
        k_agg<HH><<<(NN + 3) / 4, 256, 0, stream>>>(bufA, bufB, offs_r, csr_r, dinv_r);
        k_stats<HH><<<256, dim3(HH, 256 / HH), 0, stream>>>(bufB, partial);
        k_finalize<HH><<<1, HH, 0, stream>>>(partial, g1 + r * HH, be1 + r * HH, ab);
        k_apply<HH><<<(NN * HH / 4 + 255) / 256, 256, 0, stream>>>(bufB, ab);

        k_gemm<HH, OO><<<(NN + 63) / 64, 256, 0, stream>>>(bufB, W2 + (size_t)r * HH * OO, bufC);
        k_agg<OO><<<(NN + 7) / 8, 256, 0, stream>>>(bufC, bufD, offs_r, csr_r, dinv_r);
        k_stats<OO><<<256, dim3(OO, 256 / OO), 0, stream>>>(bufD, partial);
        k_finalize<OO><<<1, OO, 0, stream>>>(partial, g2 + r * OO, be2 + r * OO, ab);
        k_apply<OO><<<(NN * OO / 4 + 255) / 256, 256, 0, stream>>>(bufD, ab);

        k_lsm<<<(BB + 7) / 8, dim3(32, 8), 0, stream>>>(bufD, batch, out, r);
    }
}

// Round 2
// 1499.275 us; speedup vs baseline: 1.1665x; 1.1665x over previous
//
#include <hip/hip_runtime.h>
#include <math.h>

#define NN 50000
#define EE 800000
#define RR 4
#define FF 256
#define HH 128
#define OO 32
#define BB 10000
#define EPSV 1e-5f

typedef __bf16 bf16_t;
typedef __attribute__((ext_vector_type(8))) bf16_t bf16x8;
typedef __attribute__((ext_vector_type(4))) float f32x4;

__device__ __forceinline__ unsigned short f2bf(float f) {
    unsigned int u = __float_as_uint(f);
    u += 0x7fff + ((u >> 16) & 1);
    return (unsigned short)(u >> 16);
}
__device__ __forceinline__ float bf2f(unsigned short s) {
    return __uint_as_float(((unsigned int)s) << 16);
}
__device__ __forceinline__ void load_lds16(const void* g, void* l) {
    __builtin_amdgcn_global_load_lds(
        (const __attribute__((address_space(1))) unsigned int*)g,
        (__attribute__((address_space(3))) unsigned int*)l, 16, 0, 0);
}

// ---------------- conversions ----------------

__global__ void k_cvt_feat(const float* __restrict__ in, ushort* __restrict__ out) {
    int idx = blockIdx.x * 256 + threadIdx.x;  // each thread: 8 elems
    const float4* p = (const float4*)in + (size_t)idx * 2;
    float4 a = p[0], b = p[1];
    uint4 o;
    o.x = (unsigned)f2bf(a.x) | ((unsigned)f2bf(a.y) << 16);
    o.y = (unsigned)f2bf(a.z) | ((unsigned)f2bf(a.w) << 16);
    o.z = (unsigned)f2bf(b.x) | ((unsigned)f2bf(b.y) << 16);
    o.w = (unsigned)f2bf(b.z) | ((unsigned)f2bf(b.w) << 16);
    ((uint4*)out)[idx] = o;
}

__global__ void k_cvt_w1(const float* __restrict__ in, ushort* __restrict__ out) {
    int idx = blockIdx.x * 256 + threadIdx.x;  // R*F*H = 131072
    if (idx >= RR * FF * HH) return;
    int r = idx >> 15, k = (idx >> 7) & 255, n = idx & 127;
    out[r * (HH * FF) + n * FF + k] = f2bf(in[idx]);
}

__global__ void k_cvt_w2(const float* __restrict__ in, ushort* __restrict__ out) {
    int idx = blockIdx.x * 256 + threadIdx.x;  // R*H*O = 16384
    if (idx >= RR * HH * OO) return;
    int r = idx >> 12, k = (idx >> 5) & 127, n = idx & 31;
    out[r * (OO * HH) + n * HH + k] = f2bf(in[idx]);
}

// ---------------- CSR build ----------------

__global__ void k_count(const int* __restrict__ edges, int* __restrict__ deg) {
    int r = blockIdx.y;
    int e = blockIdx.x * blockDim.x + threadIdx.x;
    if (e < EE) {
        int dst = edges[(size_t)r * 2 * EE + EE + e];
        atomicAdd(&deg[r * NN + dst], 1);
    }
}

__global__ void k_scan(const int* __restrict__ deg, int* __restrict__ offs,
                       int* __restrict__ cursor, float* __restrict__ dinv) {
    int r = blockIdx.x;
    int t = threadIdx.x;
    const int C = (NN + 255) / 256;
    __shared__ int s[256];
    int begin = t * C;
    int end = begin + C; if (end > NN) end = NN;
    int sum = 0;
    for (int i = begin; i < end; ++i) sum += deg[r * NN + i];
    s[t] = sum;
    __syncthreads();
    for (int off = 1; off < 256; off <<= 1) {
        int u = (t >= off) ? s[t - off] : 0;
        __syncthreads();
        s[t] += u;
        __syncthreads();
    }
    int run = s[t] - sum;
    for (int i = begin; i < end; ++i) {
        int d = deg[r * NN + i];
        offs[r * (NN + 1) + i] = run;
        cursor[r * NN + i] = run;
        dinv[r * NN + i] = rsqrtf((float)(d + 1));
        run += d;
    }
    if (t == 255) offs[r * (NN + 1) + NN] = EE;
}

__global__ void k_fill(const int* __restrict__ edges, int* __restrict__ cursor,
                       int* __restrict__ csr) {
    int r = blockIdx.y;
    int e = blockIdx.x * blockDim.x + threadIdx.x;
    if (e < EE) {
        int src = edges[(size_t)r * 2 * EE + e];
        int dst = edges[(size_t)r * 2 * EE + EE + e];
        int pos = atomicAdd(&cursor[r * NN + dst], 1);
        csr[(size_t)r * EE + pos] = src;
    }
}

// ---------------- MFMA GEMM1: C[N][128] = A[N][256] x W1t[128][256]^T ----------------

__global__ __launch_bounds__(256) void k_mm1(const ushort* __restrict__ A,
                                             const ushort* __restrict__ Wt,
                                             ushort* __restrict__ C) {
    __shared__ __align__(16) ushort As[128 * 32];
    __shared__ __align__(16) ushort Bs[128 * 32];
    int tid = threadIdx.x;
    int lane = tid & 63, w = tid >> 6;
    int wm = w >> 1, wn = w & 1;
    int row0 = blockIdx.x * 128;
    int l15 = lane & 15, l4 = lane >> 4;

    f32x4 acc[4][4];
#pragma unroll
    for (int mf = 0; mf < 4; ++mf)
#pragma unroll
        for (int nf = 0; nf < 4; ++nf) acc[mf][nf] = (f32x4)0.f;

    for (int k0 = 0; k0 < FF; k0 += 32) {
#pragma unroll
        for (int i = 0; i < 2; ++i) {
            int chunk = i * 256 + tid;
            int ar = chunk >> 2, as_ = chunk & 3;
            int grow = row0 + ar; if (grow > NN - 1) grow = NN - 1;
            load_lds16(A + (size_t)grow * FF + k0 + as_ * 8,
                       As + (size_t)(i * 256 + w * 64) * 8);
        }
#pragma unroll
        for (int i = 0; i < 2; ++i) {
            int chunk = i * 256 + tid;
            int bn = chunk >> 2, slot = chunk & 3;
            uint4 v = *(const uint4*)(Wt + bn * FF + k0 + slot * 8);
            int sw = slot ^ ((bn >> 1) & 3);
            *(uint4*)(Bs + bn * 32 + sw * 8) = v;
        }
        __syncthreads();
        bf16x8 af[4], bfr[4];
#pragma unroll
        for (int mf = 0; mf < 4; ++mf) {
            int row = wm * 64 + mf * 16 + l15;
            af[mf] = *(const bf16x8*)(As + row * 32 + l4 * 8);
        }
#pragma unroll
        for (int nf = 0; nf < 4; ++nf) {
            int n = wn * 64 + nf * 16 + l15;
            int sw = l4 ^ ((n >> 1) & 3);
            bfr[nf] = *(const bf16x8*)(Bs + n * 32 + sw * 8);
        }
#pragma unroll
        for (int mf = 0; mf < 4; ++mf)
#pragma unroll
            for (int nf = 0; nf < 4; ++nf)
                acc[mf][nf] = __builtin_amdgcn_mfma_f32_16x16x32_bf16(af[mf], bfr[nf], acc[mf][nf], 0, 0, 0);
        __syncthreads();
    }
#pragma unroll
    for (int mf = 0; mf < 4; ++mf) {
#pragma unroll
        for (int nf = 0; nf < 4; ++nf) {
#pragma unroll
            for (int j = 0; j < 4; ++j) {
                int row = row0 + wm * 64 + mf * 16 + l4 * 4 + j;
                if (row < NN)
                    C[(size_t)row * HH + wn * 64 + nf * 16 + l15] = f2bf(acc[mf][nf][j]);
            }
        }
    }
}

// ---------------- MFMA GEMM2: C[N][32] = A[N][128] x W2t[32][128]^T ----------------

__global__ __launch_bounds__(256) void k_mm2(const ushort* __restrict__ A,
                                             const ushort* __restrict__ Wt,
                                             ushort* __restrict__ C) {
    __shared__ __align__(16) ushort As[256 * 32];
    __shared__ __align__(16) ushort Ws2[32 * 128];
    int tid = threadIdx.x;
    int lane = tid & 63, w = tid >> 6;
    int l15 = lane & 15, l4 = lane >> 4;
    int row0 = blockIdx.x * 256;

#pragma unroll
    for (int i = 0; i < 2; ++i) {
        int chunk = i * 256 + tid;        // 512 chunks
        int n = chunk >> 4, slot = chunk & 15;
        uint4 v = *(const uint4*)(Wt + n * HH + slot * 8);
        int sw = slot ^ (n & 7);
        *(uint4*)(Ws2 + n * HH + sw * 8) = v;
    }

    f32x4 acc[4][2];
#pragma unroll
    for (int mf = 0; mf < 4; ++mf)
#pragma unroll
        for (int nf = 0; nf < 2; ++nf) acc[mf][nf] = (f32x4)0.f;

    for (int k0 = 0; k0 < HH; k0 += 32) {
#pragma unroll
        for (int i = 0; i < 4; ++i) {
            int chunk = i * 256 + tid;
            int ar = chunk >> 2, slot = chunk & 3;
            int grow = row0 + ar; if (grow > NN - 1) grow = NN - 1;
            load_lds16(A + (size_t)grow * HH + k0 + slot * 8,
                       As + (size_t)(i * 256 + w * 64) * 8);
        }
        __syncthreads();
        bf16x8 af[4], bfr[2];
#pragma unroll
        for (int mf = 0; mf < 4; ++mf)
            af[mf] = *(const bf16x8*)(As + (w * 64 + mf * 16 + l15) * 32 + l4 * 8);
#pragma unroll
        for (int nf = 0; nf < 2; ++nf) {
            int n = nf * 16 + l15;
            int slot = (k0 >> 3) + l4;
            int sw = slot ^ (n & 7);
            bfr[nf] = *(const bf16x8*)(Ws2 + n * HH + sw * 8);
        }
#pragma unroll
        for (int mf = 0; mf < 4; ++mf)
#pragma unroll
            for (int nf = 0; nf < 2; ++nf)
                acc[mf][nf] = __builtin_amdgcn_mfma_f32_16x16x32_bf16(af[mf], bfr[nf], acc[mf][nf], 0, 0, 0);
        __syncthreads();
    }
#pragma unroll
    for (int mf = 0; mf < 4; ++mf) {
#pragma unroll
        for (int nf = 0; nf < 2; ++nf) {
#pragma unroll
            for (int j = 0; j < 4; ++j) {
                int row = row0 + w * 64 + mf * 16 + l4 * 4 + j;
                if (row < NN)
                    C[(size_t)row * OO + nf * 16 + l15] = f2bf(acc[mf][nf][j]);
            }
        }
    }
}

// ---------------- aggregation (bf16 in, fp32 out) ----------------

__global__ void k_agg1(const ushort* __restrict__ X, float* __restrict__ Y,
                       const int* __restrict__ offs, const int* __restrict__ csr,
                       const float* __restrict__ dinv) {
    int tid = threadIdx.x;
    int wid = tid >> 6, lane = tid & 63;
    int n = blockIdx.x * 4 + wid;
    if (n >= NN) return;
    int c = lane * 2;
    float ax = 0.f, ay = 0.f;
    int s0 = offs[n], s1 = offs[n + 1];
    for (int e = s0; e < s1; ++e) {
        int s = csr[e];
        float wgt = dinv[s];
        unsigned v = *(const unsigned*)(X + (size_t)s * HH + c);
        ax += wgt * bf2f((ushort)(v & 0xffff));
        ay += wgt * bf2f((ushort)(v >> 16));
    }
    float dn = dinv[n];
    unsigned v = *(const unsigned*)(X + (size_t)n * HH + c);
    ax += dn * bf2f((ushort)(v & 0xffff));
    ay += dn * bf2f((ushort)(v >> 16));
    float2 o; o.x = ax * dn; o.y = ay * dn;
    *(float2*)(Y + (size_t)n * HH + c) = o;
}

__global__ void k_agg2(const ushort* __restrict__ X, float* __restrict__ Y,
                       const int* __restrict__ offs, const int* __restrict__ csr,
                       const float* __restrict__ dinv) {
    int tid = threadIdx.x;
    int wid = tid >> 6, lane = tid & 63;
    int sub = lane >> 5, col = lane & 31;
    int n = blockIdx.x * 8 + wid * 2 + sub;
    if (n >= NN) return;
    float acc = 0.f;
    int s0 = offs[n], s1 = offs[n + 1];
    for (int e = s0; e < s1; ++e) {
        int s = csr[e];
        acc += dinv[s] * bf2f(X[(size_t)s * OO + col]);
    }
    float dn = dinv[n];
    acc += dn * bf2f(X[(size_t)n * OO + col]);
    Y[(size_t)n * OO + col] = acc * dn;
}

// ---------------- batchnorm ----------------

template <int D>
__global__ void k_stats(const float* __restrict__ X, float* __restrict__ partial) {
    constexpr int BY = 256 / D;
    int c = threadIdx.x;
    int ty = threadIdx.y;
    float s = 0.f, ss = 0.f;
    for (int row = blockIdx.x * BY + ty; row < NN; row += gridDim.x * BY) {
        float v = X[(size_t)row * D + c];
        s += v; ss += v * v;
    }
    __shared__ float ls[BY][D];
    __shared__ float lss[BY][D];
    ls[ty][c] = s; lss[ty][c] = ss;
    __syncthreads();
    if (ty == 0) {
#pragma unroll
        for (int y = 1; y < BY; ++y) { s += ls[y][c]; ss += lss[y][c]; }
        partial[blockIdx.x * 2 * D + c] = s;
        partial[blockIdx.x * 2 * D + D + c] = ss;
    }
}

template <int D>
__global__ void k_finalize(const float* __restrict__ partial, const float* __restrict__ g,
                           const float* __restrict__ be, float* __restrict__ ab) {
    int c = threadIdx.x;
    float s = 0.f, ss = 0.f;
    for (int i = 0; i < 256; ++i) {
        s += partial[i * 2 * D + c];
        ss += partial[i * 2 * D + D + c];
    }
    float mean = s / (float)NN;
    float var = ss / (float)NN - mean * mean;
    float rstd = rsqrtf(var + EPSV);
    float a = g[c] * rstd;
    ab[c] = a;
    ab[D + c] = be[c] - mean * a;
}

// apply1: fp32 in -> relu(bn) -> bf16 out
__global__ void k_apply1(const float* __restrict__ X, const float* __restrict__ ab,
                         ushort* __restrict__ Y) {
    int idx = blockIdx.x * 256 + threadIdx.x;  // NN*HH/4 threads
    if (idx >= NN * HH / 4) return;
    int c4 = idx & 31;
    float4 x = ((const float4*)X)[idx];
    float4 a = ((const float4*)ab)[c4];
    float4 b = ((const float4*)ab)[32 + c4];
    float y0 = fmaxf(a.x * x.x + b.x, 0.f);
    float y1 = fmaxf(a.y * x.y + b.y, 0.f);
    float y2 = fmaxf(a.z * x.z + b.z, 0.f);
    float y3 = fmaxf(a.w * x.w + b.w, 0.f);
    uint2 o;
    o.x = (unsigned)f2bf(y0) | ((unsigned)f2bf(y1) << 16);
    o.y = (unsigned)f2bf(y2) | ((unsigned)f2bf(y3) << 16);
    ((uint2*)Y)[idx] = o;
}

// apply2: fp32 in-place
template <int D>
__global__ void k_apply(float* __restrict__ X, const float* __restrict__ ab) {
    constexpr int TOT4 = NN * D / 4;
    int idx = blockIdx.x * blockDim.x + threadIdx.x;
    if (idx >= TOT4) return;
    int c4 = idx % (D / 4);
    float4 x = ((const float4*)X)[idx];
    float4 a = ((const float4*)ab)[c4];
    float4 b = ((const float4*)ab)[D / 4 + c4];
    float4 y;
    y.x = fmaxf(a.x * x.x + b.x, 0.f);
    y.y = fmaxf(a.y * x.y + b.y, 0.f);
    y.z = fmaxf(a.z * x.z + b.z, 0.f);
    y.w = fmaxf(a.w * x.w + b.w, 0.f);
    ((float4*)X)[idx] = y;
}

// ---------------- gather + log_softmax ----------------

__global__ void k_lsm(const float* __restrict__ X, const int* __restrict__ batch,
                      float* __restrict__ out, int r) {
    int tx = threadIdx.x;  // 32 = OO
    int b = blockIdx.x * blockDim.y + threadIdx.y;
    if (b >= BB) return;
    int node = batch[b];
    float v = X[(size_t)node * OO + tx];
    float m = v;
#pragma unroll
    for (int off = 16; off; off >>= 1) m = fmaxf(m, __shfl_xor(m, off, 32));
    float e = expf(v - m);
    float sum = e;
#pragma unroll
    for (int off = 16; off; off >>= 1) sum += __shfl_xor(sum, off, 32);
    out[(size_t)b * (RR * OO) + r * OO + tx] = v - m - logf(sum);
}

// ---------------- host ----------------

extern "C" void kernel_launch(void* const* d_in, const int* in_sizes, int n_in,
                              void* d_out, int out_size, void* d_ws, size_t ws_size,
                              hipStream_t stream) {
    const float* features = (const float*)d_in[0];
    const int* edges = (const int*)d_in[1];
    const int* batch = (const int*)d_in[2];
    const float* W1 = (const float*)d_in[3];
    const float* g1 = (const float*)d_in[5];
    const float* be1 = (const float*)d_in[6];
    const float* W2 = (const float*)d_in[7];
    const float* g2 = (const float*)d_in[9];
    const float* be2 = (const float*)d_in[10];
    float* out = (float*)d_out;

    char* p = (char*)d_ws;
    auto carve = [&](size_t bytes) {
        void* q = (void*)p;
        p += (bytes + 255) & ~(size_t)255;
        return q;
    };
    ushort* Fbf = (ushort*)carve((size_t)NN * FF * 2);
    ushort* W1t = (ushort*)carve((size_t)RR * FF * HH * 2);
    ushort* W2t = (ushort*)carve((size_t)RR * HH * OO * 2);
    int* deg = (int*)carve((size_t)RR * NN * 4);
    float* dinv = (float*)carve((size_t)RR * NN * 4);
    int* offs = (int*)carve((size_t)RR * (NN + 1) * 4);
    int* cursor = (int*)carve((size_t)RR * NN * 4);
    int* csr = (int*)carve((size_t)RR * EE * 4);
    ushort* bufAh = (ushort*)carve((size_t)NN * HH * 2);
    float* bufB = (float*)carve((size_t)NN * HH * 4);
    ushort* bufBh = (ushort*)carve((size_t)NN * HH * 2);
    ushort* bufCh = (ushort*)carve((size_t)NN * OO * 2);
    float* bufD = (float*)carve((size_t)NN * OO * 4);
    float* partial = (float*)carve((size_t)256 * 2 * HH * 4);
    float* ab = (float*)carve((size_t)2 * HH * 4);

    k_cvt_feat<<<NN * FF / 8 / 256, 256, 0, stream>>>(features, Fbf);
    k_cvt_w1<<<(RR * FF * HH + 255) / 256, 256, 0, stream>>>(W1, W1t);
    k_cvt_w2<<<(RR * HH * OO + 255) / 256, 256, 0, stream>>>(W2, W2t);

    hipMemsetAsync(deg, 0, (size_t)RR * NN * 4, stream);
    k_count<<<dim3((EE + 255) / 256, RR), 256, 0, stream>>>(edges, deg);
    k_scan<<<RR, 256, 0, stream>>>(deg, offs, cursor, dinv);
    k_fill<<<dim3((EE + 255) / 256, RR), 256, 0, stream>>>(edges, cursor, csr);

    for (int r = 0; r < RR; ++r) {
        const int* offs_r = offs + r * (NN + 1);
        const int* csr_r = csr + (size_t)r * EE;
        const float* dinv_r = dinv + (size_t)r * NN;

        k_mm1<<<(NN + 127) / 128, 256, 0, stream>>>(Fbf, W1t + (size_t)r * FF * HH, bufAh);
        k_agg1<<<(NN + 3) / 4, 256, 0, stream>>>(bufAh, bufB, offs_r, csr_r, dinv_r);
        k_stats<HH><<<256, dim3(HH, 256 / HH), 0, stream>>>(bufB, partial);
        k_finalize<HH><<<1, HH, 0, stream>>>(partial, g1 + r * HH, be1 + r * HH, ab);
        k_apply1<<<(NN * HH / 4 + 255) / 256, 256, 0, stream>>>(bufB, ab, bufBh);

        k_mm2<<<(NN + 255) / 256, 256, 0, stream>>>(bufBh, W2t + (size_t)r * HH * OO, bufCh);
        k_agg2<<<(NN + 7) / 8, 256, 0, stream>>>(bufCh, bufD, offs_r, csr_r, dinv_r);
        k_stats<OO><<<256, dim3(OO, 256 / OO), 0, stream>>>(bufD, partial);
        k_finalize<OO><<<1, OO, 0, stream>>>(partial, g2 + r * OO, be2 + r * OO, ab);
        k_apply<OO><<<(NN * OO / 4 + 255) / 256, 256, 0, stream>>>(bufD, ab);

        k_lsm<<<(BB + 7) / 8, dim3(32, 8), 0, stream>>>(bufD, batch, out, r);
    }
}